// Round 5
// baseline (82.589 us; speedup 1.0000x reference)
//
#include <hip/hip_runtime.h>
#include <hip/hip_bf16.h>

// Problem constants (from reference)
#define NN0   292864
#define NN1   11264
#define BB    1024
#define FF0   256
#define FF1   256
#define CC    47
#define FAN0  25
#define FAN1  10

typedef __bf16 bf16x8 __attribute__((ext_vector_type(8)));
typedef float  f32x4  __attribute__((ext_vector_type(4)));

static __device__ __forceinline__ unsigned short f2bf(float f) {
    unsigned int u = __float_as_uint(f);
    u = u + 0x7fffu + ((u >> 16) & 1u);   // round-to-nearest-even
    return (unsigned short)(u >> 16);
}
static __device__ __forceinline__ float bf2f(unsigned short u) {
    return __uint_as_float(((unsigned int)u) << 16);
}

// ---------------------------------------------------------------------------
// Kernel 1: weight transpose+concat (launched FIRST; Wt needed by fused k.)
// Wt[n][k] = bf16( k<256 ? Ws0[k][n] : Wn0[k-256][n] )
// ---------------------------------------------------------------------------
__global__ __launch_bounds__(256) void k_wconv(
    const float* __restrict__ Ws0, const float* __restrict__ Wn0,
    unsigned short* __restrict__ Wt)
{
    const int n = blockIdx.x;
    for (int k = threadIdx.x; k < 512; k += 256) {
        float v = (k < 256) ? Ws0[k * 256 + n] : Wn0[(k - 256) * 256 + n];
        Wt[n * 512 + k] = f2bf(v);
    }
}

// ---------------------------------------------------------------------------
// Kernel 2 (FUSED gather + GEMM): block = 16 output rows.
// Phase 1: 4 waves x 4 nodes: mean of 25 gathered x-rows + self -> bf16 LDS
//          A_lds[r][0:256]=self, [256:512]=mean. (eliminates A round-trip)
// Phase 2: barrier-free K-loop: A-frags from LDS, B-frags (Wt, L2-hot 256KB)
//          straight from global; wave w computes rows 0..15 x cols w*64..+64.
// h = relu(A @ Wt^T + b0) -> bf16.
// LDS row stride 520 shorts (1040B): frag lanes land 4 banks apart -> 2-way
// alias only (free, m136). 16.6 KB LDS -> no LDS occupancy cap.
// ---------------------------------------------------------------------------
__global__ __launch_bounds__(256) void k_fused0(
    const float* __restrict__ x, const int* __restrict__ src0,
    const unsigned short* __restrict__ Wt,  // [256][512] bf16 bits
    const float* __restrict__ b0,
    unsigned short* __restrict__ h)         // [11264][256] bf16 bits
{
    __shared__ unsigned short A_lds[16 * 520];

    const int t    = threadIdx.x;
    const int lane = t & 63;
    const int w    = t >> 6;
    const int rowBase = blockIdx.x * 16;    // grid 704*16 = 11264 exact
    const float4* __restrict__ x4 = (const float4*)x;

    // ---- Phase 1: gather 4 nodes per wave ----
    #pragma unroll
    for (int i = 0; i < 4; ++i) {
        const int r    = w * 4 + i;
        const int node = rowBase + r;
        const int* sp  = src0 + node * FAN0;

        float4 s = x4[(size_t)node * 64 + lane];

        float ax = 0.f, ay = 0.f, az = 0.f, aw = 0.f;
        #pragma unroll 5
        for (int e = 0; e < FAN0; ++e) {
            float4 v = x4[(size_t)sp[e] * 64 + lane];
            ax += v.x; ay += v.y; az += v.z; aw += v.w;
        }
        const float inv = 1.0f / (float)FAN0;

        ushort4 selfp, meanp;
        selfp.x = f2bf(s.x); selfp.y = f2bf(s.y); selfp.z = f2bf(s.z); selfp.w = f2bf(s.w);
        meanp.x = f2bf(ax * inv); meanp.y = f2bf(ay * inv);
        meanp.z = f2bf(az * inv); meanp.w = f2bf(aw * inv);

        *(ushort4*)(&A_lds[r * 520 + lane * 4])       = selfp;
        *(ushort4*)(&A_lds[r * 520 + 256 + lane * 4]) = meanp;
    }
    __syncthreads();

    // ---- Phase 2: GEMM 16 x 256 x 512, no further barriers ----
    const int rl = lane & 15;
    const int k8 = (lane >> 4) * 8;

    f32x4 acc[4];
    #pragma unroll
    for (int fn = 0; fn < 4; ++fn) acc[fn] = (f32x4){0.f, 0.f, 0.f, 0.f};

    for (int ki = 0; ki < 16; ++ki) {
        const int kk = ki * 32 + k8;
        bf16x8 afr = *(const bf16x8*)(&A_lds[rl * 520 + kk]);
        #pragma unroll
        for (int fn = 0; fn < 4; ++fn) {
            const int col = w * 64 + fn * 16 + rl;
            bf16x8 bfr = *(const bf16x8*)(&Wt[(size_t)col * 512 + kk]);
            acc[fn] = __builtin_amdgcn_mfma_f32_16x16x32_bf16(afr, bfr, acc[fn], 0, 0, 0);
        }
    }

    // epilogue: bias + relu -> bf16; C/D: col=lane&15, row=(lane>>4)*4+r
    #pragma unroll
    for (int fn = 0; fn < 4; ++fn) {
        const int col = w * 64 + fn * 16 + rl;
        const float bias = b0[col];
        #pragma unroll
        for (int r = 0; r < 4; ++r) {
            const int row = rowBase + (lane >> 4) * 4 + r;
            float v = acc[fn][r] + bias;
            h[(size_t)row * 256 + col] = f2bf(v > 0.f ? v : 0.f);
        }
    }
}

// ---------------------------------------------------------------------------
// Kernel 3 (unchanged): layer 1 + log_softmax, one block per output row,
// dot phase parallelized over 4 feature-quarters x 47 classes.
// ---------------------------------------------------------------------------
__global__ __launch_bounds__(256) void k_layer1(
    const unsigned short* __restrict__ h,  // [11264][256] bf16 bits
    const int* __restrict__ src1,
    const float* __restrict__ Ws1,    // [256][47]
    const float* __restrict__ Wn1,    // [256][47]
    const float* __restrict__ b1,     // [47]
    float* __restrict__ out)          // [1024][47]
{
    __shared__ float hd[256];
    __shared__ float mn[256];
    __shared__ float part[4][48];
    __shared__ float lg[CC];
    __shared__ float red[2];

    const int b = blockIdx.x;
    const int t = threadIdx.x;

    float acc = 0.f;
    const int* sp = src1 + b * FAN1;
    #pragma unroll
    for (int e = 0; e < FAN1; ++e)
        acc += bf2f(h[(size_t)sp[e] * 256 + t]);
    mn[t] = acc * (1.0f / (float)FAN1);
    hd[t] = bf2f(h[(size_t)b * 256 + t]);
    __syncthreads();

    const int p = t >> 6;       // feature quarter 0..3
    const int c = t & 63;       // class
    if (c < CC) {
        float s = 0.f;
        const int f0 = p * 64;
        #pragma unroll 8
        for (int f = f0; f < f0 + 64; ++f)
            s += hd[f] * Ws1[f * CC + c] + mn[f] * Wn1[f * CC + c];
        part[p][c] = s;
    }
    __syncthreads();

    if (t < CC)
        lg[t] = part[0][t] + part[1][t] + part[2][t] + part[3][t] + b1[t];
    __syncthreads();

    if (t == 0) {
        float m = -1e30f;
        for (int cc = 0; cc < CC; ++cc) m = fmaxf(m, lg[cc]);
        float se = 0.f;
        for (int cc = 0; cc < CC; ++cc) se += __expf(lg[cc] - m);
        red[0] = m;
        red[1] = logf(se);
    }
    __syncthreads();

    if (t < CC)
        out[(size_t)b * CC + t] = lg[t] - red[0] - red[1];
}

// ---------------------------------------------------------------------------
extern "C" void kernel_launch(void* const* d_in, const int* in_sizes, int n_in,
                              void* d_out, int out_size, void* d_ws, size_t ws_size,
                              hipStream_t stream)
{
    const float* x    = (const float*)d_in[0];
    const int*   src0 = (const int*)d_in[1];
    // d_in[2] = dst0 (structural: repeat(arange(N1),25)) -- unused
    const int*   src1 = (const int*)d_in[3];
    // d_in[4] = dst1 (structural: repeat(arange(B),10))  -- unused
    const float* Ws0  = (const float*)d_in[5];
    const float* Wn0  = (const float*)d_in[6];
    const float* b0   = (const float*)d_in[7];
    const float* Ws1  = (const float*)d_in[8];
    const float* Wn1  = (const float*)d_in[9];
    const float* b1   = (const float*)d_in[10];
    float* out = (float*)d_out;

    char* ws = (char*)d_ws;
    unsigned short* Wt = (unsigned short*)ws;                 // 256*512*2 = 262,144 B
    unsigned short* h  = (unsigned short*)(ws + 262144);      // 11264*256*2 = 5,767,168 B

    k_wconv <<<dim3(256),      dim3(256), 0, stream>>>(Ws0, Wn0, Wt);
    k_fused0<<<dim3(NN1 / 16), dim3(256), 0, stream>>>(x, src0, Wt, b0, h);
    k_layer1<<<dim3(BB),       dim3(256), 0, stream>>>(h, src1, Ws1, Wn1, b1, out);
}